// Round 11
// baseline (273.614 us; speedup 1.0000x reference)
//
#include <hip/hip_runtime.h>
#include <hip/hip_bf16.h>
#include <math.h>

// FraudGNN on MI355X. Counting-sort CSR (count -> scatter[self-offs] -> csr),
// DEGREE-SORTED node schedule + 16-nodes-per-wave gather kernels (4-lane
// groups, in-lane accumulation, 8-edge unrolled inner loop; round-8 lesson:
// line-service bound, do NOT pipeline). Round-11: FEATURE-SPLIT gather
// tables (32B/node halves, 3.2MB each -> per-XCD-L2-resident; regime-gated
// retry of round-2's split now that round-5's restructure removed the
// chain-traversal bound) — each agg runs as 2 passes of uint2 gathers.
// Dense MFMA: 64-row tiles (3 blocks/CU), pre-converted weights, Wb2
// global->LDS after MFMA1 (reg-holding spills, round-8). 9 kernels.

#define IN_C 64
#define HID 128
#define HID2 64
#define LDA 136     // LDS row stride for MFMA tiles
#define NBSHIFT 9   // 512 nodes per bucket
#define BR 512
#define P1B 256     // partition blocks (needs NBUCK <= 256: N <= 131072)

typedef short short8 __attribute__((ext_vector_type(8)));
typedef float f32x4 __attribute__((ext_vector_type(4)));
typedef float f32x2 __attribute__((ext_vector_type(2)));

__device__ inline unsigned short bfbits(float f) {
    __hip_bfloat16 h = __float2bfloat16(f);
    return *reinterpret_cast<unsigned short*>(&h);
}
__device__ inline float bflo(unsigned u) { return __uint_as_float(u << 16); }
__device__ inline float bfhi(unsigned u) { return __uint_as_float(u & 0xffff0000u); }
__device__ inline unsigned bfpack(float a, float b) {
    return ((unsigned)bfbits(b) << 16) | (unsigned)bfbits(a);
}
__device__ inline unsigned char f_to_fp8(float v) {
    return (unsigned char)(__builtin_amdgcn_cvt_pk_fp8_f32(v, v, 0, false) & 0xff);
}
__device__ inline void accum8(uint2 u, float* acc) {
    f32x2 p;
    p = __builtin_amdgcn_cvt_pk_f32_fp8((int)u.x, false); acc[0] += p[0]; acc[1] += p[1];
    p = __builtin_amdgcn_cvt_pk_f32_fp8((int)u.x, true);  acc[2] += p[0]; acc[3] += p[1];
    p = __builtin_amdgcn_cvt_pk_f32_fp8((int)u.y, false); acc[4] += p[0]; acc[5] += p[1];
    p = __builtin_amdgcn_cvt_pk_f32_fp8((int)u.y, true);  acc[6] += p[0]; acc[7] += p[1];
}

// ---- gather-loop: 8 edges / iteration, 8 uint2 (8B) gathers in flight ----
#define AGG_LOOP_U2(TBL)                                                    \
    const uint2* tbl = TBL;                                                 \
    int itmax = (m + 7) >> 3;                                               \
    int ecur = s0 + jl;                                                     \
    int hi = s1 - 1;                                                        \
    int src_a = __builtin_nontemporal_load(&srcs[max(min(ecur, hi), 0)]);   \
    int src_b = __builtin_nontemporal_load(&srcs[max(min(ecur + 4, hi), 0)]);\
    for (int it = 0; it < itmax; ++it) {                                    \
        int enx = ecur + 8;                                                 \
        int na = 0, nb = 0;                                                 \
        if (it + 1 < itmax) {                                               \
            na = __builtin_nontemporal_load(&srcs[max(min(enx, hi), 0)]);   \
            nb = __builtin_nontemporal_load(&srcs[max(min(enx + 4, hi), 0)]);\
        }                                                                   \
        int sa0 = __builtin_amdgcn_ds_swizzle(src_a, 0x1C);                 \
        int sa1 = __builtin_amdgcn_ds_swizzle(src_a, 0x3C);                 \
        int sa2 = __builtin_amdgcn_ds_swizzle(src_a, 0x5C);                 \
        int sa3 = __builtin_amdgcn_ds_swizzle(src_a, 0x7C);                 \
        int sb0 = __builtin_amdgcn_ds_swizzle(src_b, 0x1C);                 \
        int sb1 = __builtin_amdgcn_ds_swizzle(src_b, 0x3C);                 \
        int sb2 = __builtin_amdgcn_ds_swizzle(src_b, 0x5C);                 \
        int sb3 = __builtin_amdgcn_ds_swizzle(src_b, 0x7C);                 \
        uint2 u0 = tbl[(unsigned)(sa0 * 4 + jl)];                           \
        uint2 u1 = tbl[(unsigned)(sa1 * 4 + jl)];                           \
        uint2 u2 = tbl[(unsigned)(sa2 * 4 + jl)];                           \
        uint2 u3 = tbl[(unsigned)(sa3 * 4 + jl)];                           \
        uint2 u4 = tbl[(unsigned)(sb0 * 4 + jl)];                           \
        uint2 u5 = tbl[(unsigned)(sb1 * 4 + jl)];                           \
        uint2 u6 = tbl[(unsigned)(sb2 * 4 + jl)];                           \
        uint2 u7 = tbl[(unsigned)(sb3 * 4 + jl)];                           \
        int K = it * 8;                                                     \
        if (K + 0 < deg) accum8(u0, acc);                                   \
        if (K + 1 < deg) accum8(u1, acc);                                   \
        if (K + 2 < deg) accum8(u2, acc);                                   \
        if (K + 3 < deg) accum8(u3, acc);                                   \
        if (K + 4 < deg) accum8(u4, acc);                                   \
        if (K + 5 < deg) accum8(u5, acc);                                   \
        if (K + 6 < deg) accum8(u6, acc);                                   \
        if (K + 7 < deg) accum8(u7, acc);                                   \
        src_a = na; src_b = nb; ecur = enx;                                 \
    }

// ---------------- k1: bucket histogram + x->fp8 (split) + weight conv ----
// Wb1[n*128+k] = bf16(k<64 ? W1l[k][n] : W1r[k-64][n])
// Wb2[n*128+c] = bf16(n<64 ? W2l[c][n] : W2r[c][n-64])
__global__ __launch_bounds__(256) void count_kernel(
    const int* __restrict__ ei, int* __restrict__ cnt,
    const float4* __restrict__ x4, unsigned* __restrict__ xf8a,
    unsigned* __restrict__ xf8b, int* __restrict__ histg,
    int* __restrict__ gcnt2,
    const float* __restrict__ W1l, const float* __restrict__ W1r,
    const float* __restrict__ W2l, const float* __restrict__ W2r,
    unsigned short* __restrict__ Wb1, unsigned short* __restrict__ Wb2,
    int n4, int E, int EPB, int NBUCK)
{
    __shared__ int hist[256];
    int t = threadIdx.x, j = blockIdx.x;
    hist[t] = 0;
    if (j == 0) { histg[t] = 0; gcnt2[t] = 0; }   // for degree sort
    if (j < 16) {                                  // weight conversion
        int tw = j * 256 + t;
        for (int i = tw; i < 16384; i += 4096) {
            int n = i & 127, k = i >> 7;
            float v = (k < 64) ? W1l[k * HID + n] : W1r[(k - 64) * HID + n];
            Wb1[n * 128 + k] = bfbits(v);
        }
        for (int i = tw; i < 16384; i += 4096) {
            int n = i & 127, c = i >> 7;
            float v = (n < 64) ? W2l[c * HID2 + n] : W2r[c * HID2 + (n - 64)];
            Wb2[n * 128 + c] = bfbits(v);
        }
    }
    __syncthreads();
    int e0 = j * EPB, e1 = min(e0 + EPB, E);
    for (int e = e0 + t; e < e1; e += 256)
        atomicAdd(&hist[ei[E + e] >> NBSHIFT], 1);
    for (int i = j * 256 + t; i < n4; i += P1B * 256) {
        float4 f = x4[i];
        int lo = __builtin_amdgcn_cvt_pk_fp8_f32(f.x, f.y, 0, false);
        unsigned v = (unsigned)__builtin_amdgcn_cvt_pk_fp8_f32(f.z, f.w, lo, true);
        int node = i >> 4, w2 = i & 15;
        unsigned* dst = (w2 < 8) ? (xf8a + (size_t)node * 8 + w2)
                                 : (xf8b + (size_t)node * 8 + (w2 - 8));
        *dst = v;
    }
    __syncthreads();
    if (t < NBUCK) cnt[j * NBUCK + t] = hist[t];
}

// ---------------- k2: scatter with self-computed offsets ----------------
__global__ __launch_bounds__(256) void scatter_kernel(
    const int* __restrict__ ei, const int* __restrict__ cnt,
    int* __restrict__ bucket_base, int* __restrict__ row_ptr,
    int* __restrict__ part, int N, int E, int EPB, int NBUCK)
{
    __shared__ int tot[256];
    __shared__ int lofs[256];
    __shared__ int wred[4];
    int t = threadIdx.x, j = blockIdx.x;
    int lane = t & 63, w = t >> 6;
    int pre = 0, total = 0;
    if (t < NBUCK) {
        for (int jj = 0; jj < P1B; ++jj) {
            int c = cnt[jj * NBUCK + t];
            total += c;
            if (jj < j) pre += c;
        }
    }
    tot[t] = (t < NBUCK) ? total : 0;
    __syncthreads();
    int v = tot[t];
    int x = v;
    for (int off = 1; off < 64; off <<= 1) {
        int u = __shfl_up(x, off);
        if (lane >= off) x += u;
    }
    if (lane == 63) wred[w] = x;
    __syncthreads();
    int add = 0;
    for (int k = 0; k < w; ++k) add += wred[k];
    int bb = x + add - v;
    lofs[t] = bb + pre;
    if (j == 0) {
        if (t < NBUCK) bucket_base[t] = bb;
        if (t == 0) { bucket_base[NBUCK] = E; row_ptr[N] = E; }
    }
    __syncthreads();
    int e0 = j * EPB, e1 = min(e0 + EPB, E);
    for (int e = e0 + t; e < e1; e += 256) {
        int s = ei[e], d = ei[E + e];
        int b = d >> NBSHIFT;
        int p = atomicAdd(&lofs[b], 1);
        part[p] = (s << NBSHIFT) | (d & (BR - 1));
    }
}

// ---------------- k3: per-bucket CSR + degree histogram ----------------
__global__ __launch_bounds__(256) void csr_kernel(
    const int* __restrict__ part, const int* __restrict__ bucket_base,
    int* __restrict__ row_ptr, int* __restrict__ srcs,
    int* __restrict__ histg, int N)
{
    __shared__ int ncnt[BR];
    __shared__ int nofs[BR];
    __shared__ int nfill[BR];
    __shared__ int wred[4];
    __shared__ int dh[256];
    int b = blockIdx.x;
    int t = threadIdx.x, lane = t & 63, w = t >> 6;
    int node0 = b << NBSHIFT;
    int nn = min(BR, N - node0);
    int gb0 = bucket_base[b], gb1 = bucket_base[b + 1];
    ncnt[t] = 0; ncnt[t + 256] = 0; dh[t] = 0;
    __syncthreads();
    for (int i = gb0 + t; i < gb1; i += 256)
        atomicAdd(&ncnt[part[i] & (BR - 1)], 1);
    __syncthreads();
    for (int i = t; i < nn; i += 256)
        atomicAdd(&dh[min(ncnt[i], 255)], 1);
    int c0 = ncnt[2 * t], c1 = ncnt[2 * t + 1];
    int v = c0 + c1;
    int x = v;
    for (int off = 1; off < 64; off <<= 1) {
        int u = __shfl_up(x, off);
        if (lane >= off) x += u;
    }
    if (lane == 63) wred[w] = x;
    __syncthreads();
    int add = 0;
    for (int k = 0; k < w; ++k) add += wred[k];
    int exc = x + add - v;
    nofs[2 * t] = exc;          nofs[2 * t + 1] = exc + c0;
    nfill[2 * t] = exc;         nfill[2 * t + 1] = exc + c0;
    __syncthreads();
    if (dh[t]) atomicAdd(&histg[t], dh[t]);
    for (int i = t; i < nn; i += 256) row_ptr[node0 + i] = gb0 + nofs[i];
    for (int i = gb0 + t; i < gb1; i += 256) {
        int p = part[i];
        int pos = atomicAdd(&nfill[p & (BR - 1)], 1);
        srcs[gb0 + pos] = ((unsigned)p) >> NBSHIFT;
    }
}

// ---------------- k3b: degree counting-sort of node ids ----------------
__global__ __launch_bounds__(256) void dsort_kernel(
    const int* __restrict__ row_ptr, const int* __restrict__ histg,
    int* __restrict__ gcnt2, int* __restrict__ dsorted, int N)
{
    __shared__ int base[256];
    __shared__ int wred[4];
    __shared__ int lcnt[256];
    __shared__ int bbase[256];
    int t = threadIdx.x, lane = t & 63, w = t >> 6;
    int v = histg[t];
    int x = v;
    for (int off = 1; off < 64; off <<= 1) {
        int u = __shfl_up(x, off);
        if (lane >= off) x += u;
    }
    if (lane == 63) wred[w] = x;
    lcnt[t] = 0;
    __syncthreads();
    int add = 0;
    for (int k = 0; k < w; ++k) add += wred[k];
    base[t] = x + add - v;
    __syncthreads();
    int n = blockIdx.x * 256 + t;
    int bin = 0, lr = 0;
    if (n < N) {
        int deg = row_ptr[n + 1] - row_ptr[n];
        bin = min(deg, 255);
        lr = atomicAdd(&lcnt[bin], 1);
    }
    __syncthreads();
    if (lcnt[t] > 0) bbase[t] = atomicAdd(&gcnt2[t], lcnt[t]);
    __syncthreads();
    if (n < N) dsorted[base[bin] + bbase[bin] + lr] = n;
}

// ------- k4: gather-mean of one 32B half of x(fp8) -> M1 half (bf16) -----
__global__ __launch_bounds__(256) void agg1_kernel(
    const uint2* __restrict__ H, const int* __restrict__ row_ptr,
    const int* __restrict__ srcs, const int* __restrict__ dsorted,
    unsigned* __restrict__ M1u, int N, int half)
{
    int t = threadIdx.x;
    int lane = t & 63, wv = t >> 6;
    int slot = blockIdx.x * 64 + wv * 16 + (lane >> 2);
    int jl = lane & 3;
    bool live = slot < N;
    int node = dsorted[live ? slot : 0];
    int s0 = row_ptr[node], s1 = row_ptr[node + 1];
    int deg = live ? (s1 - s0) : 0;
    int m = deg;
    m = max(m, __shfl_xor(m, 4));  m = max(m, __shfl_xor(m, 8));
    m = max(m, __shfl_xor(m, 16)); m = max(m, __shfl_xor(m, 32));

    float acc[8];
#pragma unroll
    for (int i = 0; i < 8; ++i) acc[i] = 0.f;

    AGG_LOOP_U2(H)

    float scale = deg > 0 ? 1.f / (float)deg : 0.f;
    if (live) {
        uint4 o;
        o.x = bfpack(acc[0] * scale, acc[1] * scale);
        o.y = bfpack(acc[2] * scale, acc[3] * scale);
        o.z = bfpack(acc[4] * scale, acc[5] * scale);
        o.w = bfpack(acc[6] * scale, acc[7] * scale);
        ((uint4*)(M1u + (size_t)node * 32))[half * 4 + jl] = o;
    }
}

// ---------------- k5: fused dense: H1 -> G (fp8 halves), S2 (bf16) --------
// 64-row tiles: LDS 52.2 KB -> 3 blocks/CU. Wb2 global->LDS after MFMA1.
__global__ __launch_bounds__(256) void dense_kernel(
    const unsigned short* __restrict__ M1s, const float* __restrict__ x,
    const unsigned short* __restrict__ Wb1, const float* __restrict__ b1,
    const unsigned short* __restrict__ Wb2, unsigned* __restrict__ G8a,
    unsigned* __restrict__ G8b, unsigned* __restrict__ S2u, int N)
{
    __shared__ unsigned short sA[64 * LDA];
    __shared__ unsigned short sB[128 * LDA];
    int tid = threadIdx.x;
    int base = blockIdx.x * 64;

    const uint4* wb1q = (const uint4*)Wb1;
    for (int i = tid; i < 2048; i += 256) {          // W1: 128 rows x 16 uint4
        int n = i >> 4, s = i & 15;
        *(uint4*)&sB[n * LDA + s * 8] = wb1q[i];
    }
    const uint4* m1q = (const uint4*)M1s;
    const float4* xq = (const float4*)x;
    for (int i = tid; i < 512; i += 256) {           // M1: 64 rows x 8 uint4
        int r = i >> 3, s = i & 7;
        int node = min(base + r, N - 1);
        *(uint4*)&sA[r * LDA + s * 8] = m1q[(size_t)node * 8 + s];
    }
    for (int i = tid; i < 512; i += 256) {           // x: 64 rows x 8 chunks
        int r = i >> 3, s = i & 7;
        int node = min(base + r, N - 1);
        float4 f0 = xq[(size_t)node * 16 + s * 2];
        float4 f1 = xq[(size_t)node * 16 + s * 2 + 1];
        uint4 u;
        u.x = bfpack(f0.x, f0.y); u.y = bfpack(f0.z, f0.w);
        u.z = bfpack(f1.x, f1.y); u.w = bfpack(f1.z, f1.w);
        *(uint4*)&sA[r * LDA + 64 + s * 8] = u;
    }
    __syncthreads();

    int w = tid >> 6, lane = tid & 63;
    int m0 = w * 16;
    int mr = lane & 15, q = lane >> 4;
    const f32x4 zero = {0.f, 0.f, 0.f, 0.f};

    f32x4 acc[8];
#pragma unroll
    for (int nt = 0; nt < 8; ++nt) acc[nt] = zero;

#pragma unroll
    for (int kt = 0; kt < 4; ++kt) {
        short8 a0 = *reinterpret_cast<const short8*>(&sA[(m0 + mr) * LDA + kt * 32 + q * 8]);
#pragma unroll
        for (int nt = 0; nt < 8; ++nt) {
            short8 b = *reinterpret_cast<const short8*>(&sB[(nt * 16 + mr) * LDA + kt * 32 + q * 8]);
            acc[nt] = __builtin_amdgcn_mfma_f32_16x16x32_bf16(a0, b, acc[nt], 0, 0, 0);
        }
    }
    __syncthreads();

#pragma unroll
    for (int nt = 0; nt < 8; ++nt)
#pragma unroll
        for (int j = 0; j < 4; ++j) {
            int row = m0 + q * 4 + j;
            int col = nt * 16 + mr;
            float v = acc[nt][j] + b1[col];
            sA[row * LDA + col] = bfbits(fmaxf(v, 0.f));
        }
    const uint4* wb2q = (const uint4*)Wb2;
    for (int i = tid; i < 2048; i += 256) {          // W2: 128 rows x 16 uint4
        int n = i >> 4, s = i & 15;
        *(uint4*)&sB[n * LDA + s * 8] = wb2q[i];
    }
    __syncthreads();

    f32x4 acc2[8];
#pragma unroll
    for (int nt = 0; nt < 8; ++nt) acc2[nt] = zero;

#pragma unroll
    for (int kt = 0; kt < 4; ++kt) {
        short8 a0 = *reinterpret_cast<const short8*>(&sA[(m0 + mr) * LDA + kt * 32 + q * 8]);
#pragma unroll
        for (int nt = 0; nt < 8; ++nt) {
            short8 b = *reinterpret_cast<const short8*>(&sB[(nt * 16 + mr) * LDA + kt * 32 + q * 8]);
            acc2[nt] = __builtin_amdgcn_mfma_f32_16x16x32_bf16(a0, b, acc2[nt], 0, 0, 0);
        }
    }
    __syncthreads(); // stage-2 LDS reads done; reuse sA/sB as output staging

    unsigned char* sG = (unsigned char*)sA;     // [64][64] fp8
    unsigned short* sS = (unsigned short*)sB;   // [64][64] bf16
#pragma unroll
    for (int nt = 0; nt < 8; ++nt)
#pragma unroll
        for (int j = 0; j < 4; ++j) {
            int row = m0 + q * 4 + j;
            int col = nt * 16 + mr;
            float v = acc2[nt][j];
            if (col < 64) sG[row * 64 + col] = f_to_fp8(v);
            else          sS[row * 64 + (col - 64)] = bfbits(v);
        }
    __syncthreads();
    const unsigned* sGu = (const unsigned*)sG;
    for (int i = tid; i < 64 * 16; i += 256) {
        int r = i >> 4, node = base + r, wd = i & 15;
        if (node < N) {
            if (wd < 8) G8a[(size_t)node * 8 + wd] = sGu[i];
            else        G8b[(size_t)node * 8 + (wd - 8)] = sGu[i];
        }
    }
    const unsigned* sSu = (const unsigned*)sS;
    for (int i = tid; i < 64 * 32; i += 256) {
        int r = i >> 5, node = base + r;
        if (node < N) S2u[(size_t)node * 32 + (i & 31)] = sSu[i];
    }
}

// ------ k6: gather-mean of one 32B half of G(fp8) + partial FC ------------
// half 0: stage partial z in out[node]; half 1: finish + sigmoid.
__global__ __launch_bounds__(256) void agg2fc_kernel(
    const uint2* __restrict__ H, const int* __restrict__ row_ptr,
    const int* __restrict__ srcs, const int* __restrict__ dsorted,
    const unsigned* __restrict__ S2u, const float* __restrict__ b2,
    const float* __restrict__ Wfc, const float* __restrict__ bfc,
    float* __restrict__ out, int N, int half)
{
    int t = threadIdx.x;
    int lane = t & 63, wv = t >> 6;
    int slot = blockIdx.x * 64 + wv * 16 + (lane >> 2);
    int jl = lane & 3;
    bool live = slot < N;
    int node = dsorted[live ? slot : 0];
    int s0 = row_ptr[node], s1 = row_ptr[node + 1];
    int deg = live ? (s1 - s0) : 0;
    int m = deg;
    m = max(m, __shfl_xor(m, 4));  m = max(m, __shfl_xor(m, 8));
    m = max(m, __shfl_xor(m, 16)); m = max(m, __shfl_xor(m, 32));

    // hoist per-node S2 load: in flight across the whole edge loop
    uint4 sa = ((const uint4*)(S2u + (size_t)node * 32))[half * 4 + jl];

    float acc[8];
#pragma unroll
    for (int i = 0; i < 8; ++i) acc[i] = 0.f;

    AGG_LOOP_U2(H)

    float scale = deg > 0 ? 1.f / (float)deg : 0.f;
    float z = 0.f;
    if (live) {
        const float4* b4p = ((const float4*)b2) + half * 8 + jl * 2;
        const float4* w4p = ((const float4*)Wfc) + half * 8 + jl * 2;
        unsigned sw0 = sa.x, sw1 = sa.y, sw2 = sa.z, sw3 = sa.w;
        float4 b4, w4;
        b4 = b4p[0]; w4 = w4p[0];
        z += fmaxf(acc[0] * scale + bflo(sw0) + b4.x, 0.f) * w4.x;
        z += fmaxf(acc[1] * scale + bfhi(sw0) + b4.y, 0.f) * w4.y;
        z += fmaxf(acc[2] * scale + bflo(sw1) + b4.z, 0.f) * w4.z;
        z += fmaxf(acc[3] * scale + bfhi(sw1) + b4.w, 0.f) * w4.w;
        b4 = b4p[1]; w4 = w4p[1];
        z += fmaxf(acc[4] * scale + bflo(sw2) + b4.x, 0.f) * w4.x;
        z += fmaxf(acc[5] * scale + bfhi(sw2) + b4.y, 0.f) * w4.y;
        z += fmaxf(acc[6] * scale + bflo(sw3) + b4.z, 0.f) * w4.z;
        z += fmaxf(acc[7] * scale + bfhi(sw3) + b4.w, 0.f) * w4.w;
    }
    z += __shfl_xor(z, 1); z += __shfl_xor(z, 2);
    if (live && jl == 0) {
        if (half == 0) out[node] = z;                    // stage partial
        else out[node] = 1.f / (1.f + __expf(-(z + out[node] + bfc[0])));
    }
}

// ---------------- launch ----------------
static inline size_t align_up(size_t v, size_t a) { return (v + a - 1) & ~(a - 1); }

extern "C" void kernel_launch(void* const* d_in, const int* in_sizes, int n_in,
                              void* d_out, int out_size, void* d_ws, size_t ws_size,
                              hipStream_t stream) {
    const float* x   = (const float*)d_in[0];
    const int*   ei  = (const int*)d_in[1];
    const float* W1l = (const float*)d_in[2];
    const float* b1  = (const float*)d_in[3];
    const float* W1r = (const float*)d_in[4];
    const float* W2l = (const float*)d_in[5];
    const float* b2  = (const float*)d_in[6];
    const float* W2r = (const float*)d_in[7];
    const float* Wfc = (const float*)d_in[8];
    const float* bfc = (const float*)d_in[9];
    float* out = (float*)d_out;

    const int N = in_sizes[0] / IN_C;   // 100000
    const int E = in_sizes[1] / 2;      // 1600000
    const int NBUCK = (N + BR - 1) / BR;        // 196
    const int EPB = (E + P1B - 1) / P1B;        // 6250

    char* ws = (char*)d_ws;
    size_t o = 0;
    int* row_ptr  = (int*)(ws + o); o = align_up(o + (size_t)(N + 1) * 4, 256);
    int* srcs     = (int*)(ws + o); o = align_up(o + (size_t)E * 4, 256);
    int* cnt      = (int*)(ws + o); o = align_up(o + (size_t)P1B * 256 * 4, 256);
    int* bb       = (int*)(ws + o); o = align_up(o + 257 * 4, 256);
    int* histg    = (int*)(ws + o); o = align_up(o + 256 * 4, 256);
    int* gcnt2    = (int*)(ws + o); o = align_up(o + 256 * 4, 256);
    int* dsorted  = (int*)(ws + o); o = align_up(o + (size_t)N * 4, 256);
    unsigned short* Wb1 = (unsigned short*)(ws + o); o = align_up(o + 16384 * 2, 256);
    unsigned short* Wb2 = (unsigned short*)(ws + o); o = align_up(o + 16384 * 2, 256);
    // part (E*4 = 6.4 MB) aliases S2u (N*128 B = 12.8 MB): part dead after csr.
    size_t part_off = o;
    size_t sz1 = (size_t)E * 4, sz2 = (size_t)N * 128;
    o = align_up(part_off + (sz1 > sz2 ? sz1 : sz2), 256);
    int* part = (int*)(ws + part_off);
    unsigned* S2u = (unsigned*)(ws + part_off);
    unsigned* xf8a = (unsigned*)(ws + o); o = align_up(o + (size_t)N * 32, 256);
    unsigned* xf8b = (unsigned*)(ws + o); o = align_up(o + (size_t)N * 32, 256);
    unsigned* M1u  = (unsigned*)(ws + o); o = align_up(o + (size_t)N * 128, 256);
    unsigned* G8a  = (unsigned*)(ws + o); o = align_up(o + (size_t)N * 32, 256);
    unsigned* G8b  = (unsigned*)(ws + o); o = align_up(o + (size_t)N * 32, 256);

    count_kernel<<<P1B, 256, 0, stream>>>(ei, cnt, (const float4*)x, xf8a, xf8b,
                                          histg, gcnt2, W1l, W1r, W2l, W2r,
                                          Wb1, Wb2, N * 16, E, EPB, NBUCK);
    scatter_kernel<<<P1B, 256, 0, stream>>>(ei, cnt, bb, row_ptr, part,
                                            N, E, EPB, NBUCK);
    csr_kernel<<<NBUCK, 256, 0, stream>>>(part, bb, row_ptr, srcs, histg, N);
    dsort_kernel<<<(N + 255) / 256, 256, 0, stream>>>(row_ptr, histg, gcnt2,
                                                      dsorted, N);

    int gab = (N + 63) / 64;
    agg1_kernel<<<gab, 256, 0, stream>>>((const uint2*)xf8a, row_ptr, srcs,
                                         dsorted, M1u, N, 0);
    agg1_kernel<<<gab, 256, 0, stream>>>((const uint2*)xf8b, row_ptr, srcs,
                                         dsorted, M1u, N, 1);
    dense_kernel<<<(N + 63) / 64, 256, 0, stream>>>(
        (const unsigned short*)M1u, x, Wb1, b1, Wb2, G8a, G8b, S2u, N);
    agg2fc_kernel<<<gab, 256, 0, stream>>>((const uint2*)G8a, row_ptr, srcs,
                                           dsorted, S2u, b2, Wfc, bfc, out, N, 0);
    agg2fc_kernel<<<gab, 256, 0, stream>>>((const uint2*)G8b, row_ptr, srcs,
                                           dsorted, S2u, b2, Wfc, bfc, out, N, 1);
}

// Round 13
// 235.313 us; speedup vs baseline: 1.1628x; 1.1628x over previous
//
#include <hip/hip_runtime.h>
#include <hip/hip_bf16.h>
#include <math.h>

// FraudGNN on MI355X — BEST CONFIGURATION (round 10, 235.7 µs), restored.
// (Round-11 feature-split retry regressed +38 µs: gathers are
// random-line-REQUEST-service bound; split doubles stream/launch overhead
// without reducing request count — falsified in both regimes, r2 & r11.)
// Structure: counting-sort CSR (count -> scatter[self-offs] -> csr),
// DEGREE-SORTED node schedule + 16-nodes-per-wave gather kernels (4-lane
// groups, dwordx4 gathers, in-lane accumulation, 8-edge unrolled loop;
// r8: do NOT software-pipeline). Dense MFMA with 64-row tiles (3 blocks/CU,
// r9), pre-converted bf16 weights (folded into count), vectorized uint4
// staging, Wb2 global->LDS after MFMA1 (r8: reg-holding spills).
// 7 kernels.

#define IN_C 64
#define HID 128
#define HID2 64
#define LDA 136     // LDS row stride for MFMA tiles
#define NBSHIFT 9   // 512 nodes per bucket
#define BR 512
#define P1B 256     // partition blocks (needs NBUCK <= 256: N <= 131072)

typedef short short8 __attribute__((ext_vector_type(8)));
typedef float f32x4 __attribute__((ext_vector_type(4)));
typedef float f32x2 __attribute__((ext_vector_type(2)));

__device__ inline unsigned short bfbits(float f) {
    __hip_bfloat16 h = __float2bfloat16(f);
    return *reinterpret_cast<unsigned short*>(&h);
}
__device__ inline float bflo(unsigned u) { return __uint_as_float(u << 16); }
__device__ inline float bfhi(unsigned u) { return __uint_as_float(u & 0xffff0000u); }
__device__ inline unsigned bfpack(float a, float b) {
    return ((unsigned)bfbits(b) << 16) | (unsigned)bfbits(a);
}
__device__ inline unsigned char f_to_fp8(float v) {
    return (unsigned char)(__builtin_amdgcn_cvt_pk_fp8_f32(v, v, 0, false) & 0xff);
}
__device__ inline void accum16(uint4 u, float* acc) {
    f32x2 p;
    p = __builtin_amdgcn_cvt_pk_f32_fp8((int)u.x, false); acc[0] += p[0];  acc[1] += p[1];
    p = __builtin_amdgcn_cvt_pk_f32_fp8((int)u.x, true);  acc[2] += p[0];  acc[3] += p[1];
    p = __builtin_amdgcn_cvt_pk_f32_fp8((int)u.y, false); acc[4] += p[0];  acc[5] += p[1];
    p = __builtin_amdgcn_cvt_pk_f32_fp8((int)u.y, true);  acc[6] += p[0];  acc[7] += p[1];
    p = __builtin_amdgcn_cvt_pk_f32_fp8((int)u.z, false); acc[8] += p[0];  acc[9] += p[1];
    p = __builtin_amdgcn_cvt_pk_f32_fp8((int)u.z, true);  acc[10] += p[0]; acc[11] += p[1];
    p = __builtin_amdgcn_cvt_pk_f32_fp8((int)u.w, false); acc[12] += p[0]; acc[13] += p[1];
    p = __builtin_amdgcn_cvt_pk_f32_fp8((int)u.w, true);  acc[14] += p[0]; acc[15] += p[1];
}

// ---- shared gather-loop body: 8 edges / iteration, 8 gathers in flight ----
#define AGG_LOOP(TBL)                                                       \
    const uint4* tbl = TBL;                                                 \
    int itmax = (m + 7) >> 3;                                               \
    int ecur = s0 + jl;                                                     \
    int hi = s1 - 1;                                                        \
    int src_a = __builtin_nontemporal_load(&srcs[max(min(ecur, hi), 0)]);   \
    int src_b = __builtin_nontemporal_load(&srcs[max(min(ecur + 4, hi), 0)]);\
    for (int it = 0; it < itmax; ++it) {                                    \
        int enx = ecur + 8;                                                 \
        int na = 0, nb = 0;                                                 \
        if (it + 1 < itmax) {                                               \
            na = __builtin_nontemporal_load(&srcs[max(min(enx, hi), 0)]);   \
            nb = __builtin_nontemporal_load(&srcs[max(min(enx + 4, hi), 0)]);\
        }                                                                   \
        int sa0 = __builtin_amdgcn_ds_swizzle(src_a, 0x1C);                 \
        int sa1 = __builtin_amdgcn_ds_swizzle(src_a, 0x3C);                 \
        int sa2 = __builtin_amdgcn_ds_swizzle(src_a, 0x5C);                 \
        int sa3 = __builtin_amdgcn_ds_swizzle(src_a, 0x7C);                 \
        int sb0 = __builtin_amdgcn_ds_swizzle(src_b, 0x1C);                 \
        int sb1 = __builtin_amdgcn_ds_swizzle(src_b, 0x3C);                 \
        int sb2 = __builtin_amdgcn_ds_swizzle(src_b, 0x5C);                 \
        int sb3 = __builtin_amdgcn_ds_swizzle(src_b, 0x7C);                 \
        uint4 u0 = tbl[(unsigned)(sa0 * 4 + jl)];                           \
        uint4 u1 = tbl[(unsigned)(sa1 * 4 + jl)];                           \
        uint4 u2 = tbl[(unsigned)(sa2 * 4 + jl)];                           \
        uint4 u3 = tbl[(unsigned)(sa3 * 4 + jl)];                           \
        uint4 u4 = tbl[(unsigned)(sb0 * 4 + jl)];                           \
        uint4 u5 = tbl[(unsigned)(sb1 * 4 + jl)];                           \
        uint4 u6 = tbl[(unsigned)(sb2 * 4 + jl)];                           \
        uint4 u7 = tbl[(unsigned)(sb3 * 4 + jl)];                           \
        int K = it * 8;                                                     \
        if (K + 0 < deg) accum16(u0, acc);                                  \
        if (K + 1 < deg) accum16(u1, acc);                                  \
        if (K + 2 < deg) accum16(u2, acc);                                  \
        if (K + 3 < deg) accum16(u3, acc);                                  \
        if (K + 4 < deg) accum16(u4, acc);                                  \
        if (K + 5 < deg) accum16(u5, acc);                                  \
        if (K + 6 < deg) accum16(u6, acc);                                  \
        if (K + 7 < deg) accum16(u7, acc);                                  \
        src_a = na; src_b = nb; ecur = enx;                                 \
    }

// ---------------- k1: bucket histogram + x->fp8 + weight conversion ------
// Wb1[n*128+k] = bf16(k<64 ? W1l[k][n] : W1r[k-64][n])
// Wb2[n*128+c] = bf16(n<64 ? W2l[c][n] : W2r[c][n-64])
__global__ __launch_bounds__(256) void count_kernel(
    const int* __restrict__ ei, int* __restrict__ cnt,
    const float4* __restrict__ x4, unsigned* __restrict__ xf8,
    int* __restrict__ histg, int* __restrict__ gcnt2,
    const float* __restrict__ W1l, const float* __restrict__ W1r,
    const float* __restrict__ W2l, const float* __restrict__ W2r,
    unsigned short* __restrict__ Wb1, unsigned short* __restrict__ Wb2,
    int n4, int E, int EPB, int NBUCK)
{
    __shared__ int hist[256];
    int t = threadIdx.x, j = blockIdx.x;
    hist[t] = 0;
    if (j == 0) { histg[t] = 0; gcnt2[t] = 0; }   // for degree sort
    if (j < 16) {                                  // weight conversion
        int tw = j * 256 + t;
        for (int i = tw; i < 16384; i += 4096) {
            int n = i & 127, k = i >> 7;
            float v = (k < 64) ? W1l[k * HID + n] : W1r[(k - 64) * HID + n];
            Wb1[n * 128 + k] = bfbits(v);
        }
        for (int i = tw; i < 16384; i += 4096) {
            int n = i & 127, c = i >> 7;
            float v = (n < 64) ? W2l[c * HID2 + n] : W2r[c * HID2 + (n - 64)];
            Wb2[n * 128 + c] = bfbits(v);
        }
    }
    __syncthreads();
    int e0 = j * EPB, e1 = min(e0 + EPB, E);
    for (int e = e0 + t; e < e1; e += 256)
        atomicAdd(&hist[ei[E + e] >> NBSHIFT], 1);
    for (int i = j * 256 + t; i < n4; i += P1B * 256) {
        float4 f = x4[i];
        int lo = __builtin_amdgcn_cvt_pk_fp8_f32(f.x, f.y, 0, false);
        xf8[i] = (unsigned)__builtin_amdgcn_cvt_pk_fp8_f32(f.z, f.w, lo, true);
    }
    __syncthreads();
    if (t < NBUCK) cnt[j * NBUCK + t] = hist[t];
}

// ---------------- k2: scatter with self-computed offsets ----------------
__global__ __launch_bounds__(256) void scatter_kernel(
    const int* __restrict__ ei, const int* __restrict__ cnt,
    int* __restrict__ bucket_base, int* __restrict__ row_ptr,
    int* __restrict__ part, int N, int E, int EPB, int NBUCK)
{
    __shared__ int tot[256];
    __shared__ int lofs[256];
    __shared__ int wred[4];
    int t = threadIdx.x, j = blockIdx.x;
    int lane = t & 63, w = t >> 6;
    int pre = 0, total = 0;
    if (t < NBUCK) {
        for (int jj = 0; jj < P1B; ++jj) {
            int c = cnt[jj * NBUCK + t];
            total += c;
            if (jj < j) pre += c;
        }
    }
    tot[t] = (t < NBUCK) ? total : 0;
    __syncthreads();
    int v = tot[t];
    int x = v;
    for (int off = 1; off < 64; off <<= 1) {
        int u = __shfl_up(x, off);
        if (lane >= off) x += u;
    }
    if (lane == 63) wred[w] = x;
    __syncthreads();
    int add = 0;
    for (int k = 0; k < w; ++k) add += wred[k];
    int bb = x + add - v;
    lofs[t] = bb + pre;
    if (j == 0) {
        if (t < NBUCK) bucket_base[t] = bb;
        if (t == 0) { bucket_base[NBUCK] = E; row_ptr[N] = E; }
    }
    __syncthreads();
    int e0 = j * EPB, e1 = min(e0 + EPB, E);
    for (int e = e0 + t; e < e1; e += 256) {
        int s = ei[e], d = ei[E + e];
        int b = d >> NBSHIFT;
        int p = atomicAdd(&lofs[b], 1);
        part[p] = (s << NBSHIFT) | (d & (BR - 1));
    }
}

// ---------------- k3: per-bucket CSR + degree histogram ----------------
__global__ __launch_bounds__(256) void csr_kernel(
    const int* __restrict__ part, const int* __restrict__ bucket_base,
    int* __restrict__ row_ptr, int* __restrict__ srcs,
    int* __restrict__ histg, int N)
{
    __shared__ int ncnt[BR];
    __shared__ int nofs[BR];
    __shared__ int nfill[BR];
    __shared__ int wred[4];
    __shared__ int dh[256];
    int b = blockIdx.x;
    int t = threadIdx.x, lane = t & 63, w = t >> 6;
    int node0 = b << NBSHIFT;
    int nn = min(BR, N - node0);
    int gb0 = bucket_base[b], gb1 = bucket_base[b + 1];
    ncnt[t] = 0; ncnt[t + 256] = 0; dh[t] = 0;
    __syncthreads();
    for (int i = gb0 + t; i < gb1; i += 256)
        atomicAdd(&ncnt[part[i] & (BR - 1)], 1);
    __syncthreads();
    for (int i = t; i < nn; i += 256)
        atomicAdd(&dh[min(ncnt[i], 255)], 1);
    int c0 = ncnt[2 * t], c1 = ncnt[2 * t + 1];
    int v = c0 + c1;
    int x = v;
    for (int off = 1; off < 64; off <<= 1) {
        int u = __shfl_up(x, off);
        if (lane >= off) x += u;
    }
    if (lane == 63) wred[w] = x;
    __syncthreads();
    int add = 0;
    for (int k = 0; k < w; ++k) add += wred[k];
    int exc = x + add - v;
    nofs[2 * t] = exc;          nofs[2 * t + 1] = exc + c0;
    nfill[2 * t] = exc;         nfill[2 * t + 1] = exc + c0;
    __syncthreads();
    if (dh[t]) atomicAdd(&histg[t], dh[t]);
    for (int i = t; i < nn; i += 256) row_ptr[node0 + i] = gb0 + nofs[i];
    for (int i = gb0 + t; i < gb1; i += 256) {
        int p = part[i];
        int pos = atomicAdd(&nfill[p & (BR - 1)], 1);
        srcs[gb0 + pos] = ((unsigned)p) >> NBSHIFT;
    }
}

// ---------------- k3b: degree counting-sort of node ids ----------------
__global__ __launch_bounds__(256) void dsort_kernel(
    const int* __restrict__ row_ptr, const int* __restrict__ histg,
    int* __restrict__ gcnt2, int* __restrict__ dsorted, int N)
{
    __shared__ int base[256];
    __shared__ int wred[4];
    __shared__ int lcnt[256];
    __shared__ int bbase[256];
    int t = threadIdx.x, lane = t & 63, w = t >> 6;
    int v = histg[t];
    int x = v;
    for (int off = 1; off < 64; off <<= 1) {
        int u = __shfl_up(x, off);
        if (lane >= off) x += u;
    }
    if (lane == 63) wred[w] = x;
    lcnt[t] = 0;
    __syncthreads();
    int add = 0;
    for (int k = 0; k < w; ++k) add += wred[k];
    base[t] = x + add - v;
    __syncthreads();
    int n = blockIdx.x * 256 + t;
    int bin = 0, lr = 0;
    if (n < N) {
        int deg = row_ptr[n + 1] - row_ptr[n];
        bin = min(deg, 255);
        lr = atomicAdd(&lcnt[bin], 1);
    }
    __syncthreads();
    if (lcnt[t] > 0) bbase[t] = atomicAdd(&gcnt2[t], lcnt[t]);
    __syncthreads();
    if (n < N) dsorted[base[bin] + bbase[bin] + lr] = n;
}

// ---------------- k4: gather-mean of x(fp8) -> M1 (bf16) ----------------
__global__ __launch_bounds__(256) void agg1_kernel(
    const uint4* __restrict__ xf8q, const int* __restrict__ row_ptr,
    const int* __restrict__ srcs, const int* __restrict__ dsorted,
    unsigned* __restrict__ M1u, int N)
{
    int t = threadIdx.x;
    int lane = t & 63, wv = t >> 6;
    int slot = blockIdx.x * 64 + wv * 16 + (lane >> 2);
    int jl = lane & 3;
    bool live = slot < N;
    int node = dsorted[live ? slot : 0];
    int s0 = row_ptr[node], s1 = row_ptr[node + 1];
    int deg = live ? (s1 - s0) : 0;
    int m = deg;
    m = max(m, __shfl_xor(m, 4));  m = max(m, __shfl_xor(m, 8));
    m = max(m, __shfl_xor(m, 16)); m = max(m, __shfl_xor(m, 32));

    float acc[16];
#pragma unroll
    for (int i = 0; i < 16; ++i) acc[i] = 0.f;

    AGG_LOOP(xf8q)

    float scale = deg > 0 ? 1.f / (float)deg : 0.f;
    if (live) {
        uint4 o0, o1;
        o0.x = bfpack(acc[0] * scale, acc[1] * scale);
        o0.y = bfpack(acc[2] * scale, acc[3] * scale);
        o0.z = bfpack(acc[4] * scale, acc[5] * scale);
        o0.w = bfpack(acc[6] * scale, acc[7] * scale);
        o1.x = bfpack(acc[8] * scale, acc[9] * scale);
        o1.y = bfpack(acc[10] * scale, acc[11] * scale);
        o1.z = bfpack(acc[12] * scale, acc[13] * scale);
        o1.w = bfpack(acc[14] * scale, acc[15] * scale);
        uint4* dst = (uint4*)(M1u + (size_t)node * 32) + jl * 2;
        dst[0] = o0; dst[1] = o1;
    }
}

// ---------------- k5: fused dense: H1 -> G (fp8), S2 (bf16) ----------------
// 64-row tiles: LDS 52.2 KB -> 3 blocks/CU. Vectorized staging; Wb2 loaded
// global->LDS after MFMA1 (L2-hot, no spill).
__global__ __launch_bounds__(256) void dense_kernel(
    const unsigned short* __restrict__ M1s, const float* __restrict__ x,
    const unsigned short* __restrict__ Wb1, const float* __restrict__ b1,
    const unsigned short* __restrict__ Wb2, unsigned* __restrict__ G8,
    unsigned* __restrict__ S2u, int N)
{
    __shared__ unsigned short sA[64 * LDA];
    __shared__ unsigned short sB[128 * LDA];
    int tid = threadIdx.x;
    int base = blockIdx.x * 64;

    const uint4* wb1q = (const uint4*)Wb1;
    for (int i = tid; i < 2048; i += 256) {          // W1: 128 rows x 16 uint4
        int n = i >> 4, s = i & 15;
        *(uint4*)&sB[n * LDA + s * 8] = wb1q[i];
    }
    const uint4* m1q = (const uint4*)M1s;
    const float4* xq = (const float4*)x;
    for (int i = tid; i < 512; i += 256) {           // M1: 64 rows x 8 uint4
        int r = i >> 3, s = i & 7;
        int node = min(base + r, N - 1);
        *(uint4*)&sA[r * LDA + s * 8] = m1q[(size_t)node * 8 + s];
    }
    for (int i = tid; i < 512; i += 256) {           // x: 64 rows x 8 chunks
        int r = i >> 3, s = i & 7;
        int node = min(base + r, N - 1);
        float4 f0 = xq[(size_t)node * 16 + s * 2];
        float4 f1 = xq[(size_t)node * 16 + s * 2 + 1];
        uint4 u;
        u.x = bfpack(f0.x, f0.y); u.y = bfpack(f0.z, f0.w);
        u.z = bfpack(f1.x, f1.y); u.w = bfpack(f1.z, f1.w);
        *(uint4*)&sA[r * LDA + 64 + s * 8] = u;
    }
    __syncthreads();

    int w = tid >> 6, lane = tid & 63;
    int m0 = w * 16;
    int mr = lane & 15, q = lane >> 4;
    const f32x4 zero = {0.f, 0.f, 0.f, 0.f};

    f32x4 acc[8];
#pragma unroll
    for (int nt = 0; nt < 8; ++nt) acc[nt] = zero;

#pragma unroll
    for (int kt = 0; kt < 4; ++kt) {
        short8 a0 = *reinterpret_cast<const short8*>(&sA[(m0 + mr) * LDA + kt * 32 + q * 8]);
#pragma unroll
        for (int nt = 0; nt < 8; ++nt) {
            short8 b = *reinterpret_cast<const short8*>(&sB[(nt * 16 + mr) * LDA + kt * 32 + q * 8]);
            acc[nt] = __builtin_amdgcn_mfma_f32_16x16x32_bf16(a0, b, acc[nt], 0, 0, 0);
        }
    }
    __syncthreads();

#pragma unroll
    for (int nt = 0; nt < 8; ++nt)
#pragma unroll
        for (int j = 0; j < 4; ++j) {
            int row = m0 + q * 4 + j;
            int col = nt * 16 + mr;
            float v = acc[nt][j] + b1[col];
            sA[row * LDA + col] = bfbits(fmaxf(v, 0.f));
        }
    const uint4* wb2q = (const uint4*)Wb2;
    for (int i = tid; i < 2048; i += 256) {          // W2: 128 rows x 16 uint4
        int n = i >> 4, s = i & 15;
        *(uint4*)&sB[n * LDA + s * 8] = wb2q[i];
    }
    __syncthreads();

    f32x4 acc2[8];
#pragma unroll
    for (int nt = 0; nt < 8; ++nt) acc2[nt] = zero;

#pragma unroll
    for (int kt = 0; kt < 4; ++kt) {
        short8 a0 = *reinterpret_cast<const short8*>(&sA[(m0 + mr) * LDA + kt * 32 + q * 8]);
#pragma unroll
        for (int nt = 0; nt < 8; ++nt) {
            short8 b = *reinterpret_cast<const short8*>(&sB[(nt * 16 + mr) * LDA + kt * 32 + q * 8]);
            acc2[nt] = __builtin_amdgcn_mfma_f32_16x16x32_bf16(a0, b, acc2[nt], 0, 0, 0);
        }
    }
    __syncthreads(); // stage-2 LDS reads done; reuse sA/sB as output staging

    unsigned char* sG = (unsigned char*)sA;     // [64][64] fp8
    unsigned short* sS = (unsigned short*)sB;   // [64][64] bf16
#pragma unroll
    for (int nt = 0; nt < 8; ++nt)
#pragma unroll
        for (int j = 0; j < 4; ++j) {
            int row = m0 + q * 4 + j;
            int col = nt * 16 + mr;
            float v = acc2[nt][j];
            if (col < 64) sG[row * 64 + col] = f_to_fp8(v);
            else          sS[row * 64 + (col - 64)] = bfbits(v);
        }
    __syncthreads();
    const unsigned* sGu = (const unsigned*)sG;
    for (int i = tid; i < 64 * 16; i += 256) {
        int r = i >> 4, node = base + r;
        if (node < N) G8[(size_t)node * 16 + (i & 15)] = sGu[i];
    }
    const unsigned* sSu = (const unsigned*)sS;
    for (int i = tid; i < 64 * 32; i += 256) {
        int r = i >> 5, node = base + r;
        if (node < N) S2u[(size_t)node * 32 + (i & 31)] = sSu[i];
    }
}

// ---------------- k6: gather-mean of G(fp8) + FC + sigmoid ----------------
__global__ __launch_bounds__(256) void agg2fc_kernel(
    const uint4* __restrict__ G8q, const int* __restrict__ row_ptr,
    const int* __restrict__ srcs, const int* __restrict__ dsorted,
    const unsigned* __restrict__ S2u, const float* __restrict__ b2,
    const float* __restrict__ Wfc, const float* __restrict__ bfc,
    float* __restrict__ out, int N)
{
    int t = threadIdx.x;
    int lane = t & 63, wv = t >> 6;
    int slot = blockIdx.x * 64 + wv * 16 + (lane >> 2);
    int jl = lane & 3;
    bool live = slot < N;
    int node = dsorted[live ? slot : 0];
    int s0 = row_ptr[node], s1 = row_ptr[node + 1];
    int deg = live ? (s1 - s0) : 0;
    int m = deg;
    m = max(m, __shfl_xor(m, 4));  m = max(m, __shfl_xor(m, 8));
    m = max(m, __shfl_xor(m, 16)); m = max(m, __shfl_xor(m, 32));

    // hoist per-node S2 load: in flight across the whole edge loop
    const uint4* s2p = (const uint4*)(S2u + (size_t)node * 32) + jl * 2;
    uint4 sa = s2p[0], sb = s2p[1];

    float acc[16];
#pragma unroll
    for (int i = 0; i < 16; ++i) acc[i] = 0.f;

    AGG_LOOP(G8q)

    float scale = deg > 0 ? 1.f / (float)deg : 0.f;
    float z = 0.f;
    if (live) {
        const float4* b4p = ((const float4*)b2) + jl * 4;
        const float4* w4p = ((const float4*)Wfc) + jl * 4;
        unsigned sw0 = sa.x, sw1 = sa.y, sw2 = sa.z, sw3 = sa.w;
        unsigned sw4 = sb.x, sw5 = sb.y, sw6 = sb.z, sw7 = sb.w;
        float4 b4, w4;
        b4 = b4p[0]; w4 = w4p[0];
        z += fmaxf(acc[0]  * scale + bflo(sw0) + b4.x, 0.f) * w4.x;
        z += fmaxf(acc[1]  * scale + bfhi(sw0) + b4.y, 0.f) * w4.y;
        z += fmaxf(acc[2]  * scale + bflo(sw1) + b4.z, 0.f) * w4.z;
        z += fmaxf(acc[3]  * scale + bfhi(sw1) + b4.w, 0.f) * w4.w;
        b4 = b4p[1]; w4 = w4p[1];
        z += fmaxf(acc[4]  * scale + bflo(sw2) + b4.x, 0.f) * w4.x;
        z += fmaxf(acc[5]  * scale + bfhi(sw2) + b4.y, 0.f) * w4.y;
        z += fmaxf(acc[6]  * scale + bflo(sw3) + b4.z, 0.f) * w4.z;
        z += fmaxf(acc[7]  * scale + bfhi(sw3) + b4.w, 0.f) * w4.w;
        b4 = b4p[2]; w4 = w4p[2];
        z += fmaxf(acc[8]  * scale + bflo(sw4) + b4.x, 0.f) * w4.x;
        z += fmaxf(acc[9]  * scale + bfhi(sw4) + b4.y, 0.f) * w4.y;
        z += fmaxf(acc[10] * scale + bflo(sw5) + b4.z, 0.f) * w4.z;
        z += fmaxf(acc[11] * scale + bfhi(sw5) + b4.w, 0.f) * w4.w;
        b4 = b4p[3]; w4 = w4p[3];
        z += fmaxf(acc[12] * scale + bflo(sw6) + b4.x, 0.f) * w4.x;
        z += fmaxf(acc[13] * scale + bfhi(sw6) + b4.y, 0.f) * w4.y;
        z += fmaxf(acc[14] * scale + bflo(sw7) + b4.z, 0.f) * w4.z;
        z += fmaxf(acc[15] * scale + bfhi(sw7) + b4.w, 0.f) * w4.w;
    }
    z += __shfl_xor(z, 1); z += __shfl_xor(z, 2);
    if (live && jl == 0) out[node] = 1.f / (1.f + __expf(-(z + bfc[0])));
}

// ---------------- launch ----------------
static inline size_t align_up(size_t v, size_t a) { return (v + a - 1) & ~(a - 1); }

extern "C" void kernel_launch(void* const* d_in, const int* in_sizes, int n_in,
                              void* d_out, int out_size, void* d_ws, size_t ws_size,
                              hipStream_t stream) {
    const float* x   = (const float*)d_in[0];
    const int*   ei  = (const int*)d_in[1];
    const float* W1l = (const float*)d_in[2];
    const float* b1  = (const float*)d_in[3];
    const float* W1r = (const float*)d_in[4];
    const float* W2l = (const float*)d_in[5];
    const float* b2  = (const float*)d_in[6];
    const float* W2r = (const float*)d_in[7];
    const float* Wfc = (const float*)d_in[8];
    const float* bfc = (const float*)d_in[9];
    float* out = (float*)d_out;

    const int N = in_sizes[0] / IN_C;   // 100000
    const int E = in_sizes[1] / 2;      // 1600000
    const int NBUCK = (N + BR - 1) / BR;        // 196
    const int EPB = (E + P1B - 1) / P1B;        // 6250

    char* ws = (char*)d_ws;
    size_t o = 0;
    int* row_ptr  = (int*)(ws + o); o = align_up(o + (size_t)(N + 1) * 4, 256);
    int* srcs     = (int*)(ws + o); o = align_up(o + (size_t)E * 4, 256);
    int* cnt      = (int*)(ws + o); o = align_up(o + (size_t)P1B * 256 * 4, 256);
    int* bb       = (int*)(ws + o); o = align_up(o + 257 * 4, 256);
    int* histg    = (int*)(ws + o); o = align_up(o + 256 * 4, 256);
    int* gcnt2    = (int*)(ws + o); o = align_up(o + 256 * 4, 256);
    int* dsorted  = (int*)(ws + o); o = align_up(o + (size_t)N * 4, 256);
    unsigned short* Wb1 = (unsigned short*)(ws + o); o = align_up(o + 16384 * 2, 256);
    unsigned short* Wb2 = (unsigned short*)(ws + o); o = align_up(o + 16384 * 2, 256);
    // part (E*4 = 6.4 MB) aliases S2u (N*128 B = 12.8 MB): part dead after csr.
    size_t part_off = o;
    size_t sz1 = (size_t)E * 4, sz2 = (size_t)N * 128;
    o = align_up(part_off + (sz1 > sz2 ? sz1 : sz2), 256);
    int* part = (int*)(ws + part_off);
    unsigned* S2u = (unsigned*)(ws + part_off);
    unsigned* xf8 = (unsigned*)(ws + o); o = align_up(o + (size_t)N * 16 * 4, 256);
    unsigned* M1u = (unsigned*)(ws + o); o = align_up(o + (size_t)N * 32 * 4, 256);
    unsigned* G8  = (unsigned*)(ws + o); o = align_up(o + (size_t)N * 16 * 4, 256);

    count_kernel<<<P1B, 256, 0, stream>>>(ei, cnt, (const float4*)x, xf8,
                                          histg, gcnt2, W1l, W1r, W2l, W2r,
                                          Wb1, Wb2, N * 16, E, EPB, NBUCK);
    scatter_kernel<<<P1B, 256, 0, stream>>>(ei, cnt, bb, row_ptr, part,
                                            N, E, EPB, NBUCK);
    csr_kernel<<<NBUCK, 256, 0, stream>>>(part, bb, row_ptr, srcs, histg, N);
    dsort_kernel<<<(N + 255) / 256, 256, 0, stream>>>(row_ptr, histg, gcnt2,
                                                      dsorted, N);

    int gab = (N + 63) / 64;
    agg1_kernel<<<gab, 256, 0, stream>>>((const uint4*)xf8, row_ptr, srcs,
                                         dsorted, M1u, N);
    dense_kernel<<<(N + 63) / 64, 256, 0, stream>>>(
        (const unsigned short*)M1u, x, Wb1, b1, Wb2, G8, S2u, N);
    agg2fc_kernel<<<gab, 256, 0, stream>>>((const uint4*)G8, row_ptr, srcs,
                                           dsorted, S2u, b2, Wfc, bfc, out, N);
}